// Round 6
// baseline (1048.288 us; speedup 1.0000x reference)
//
#include <hip/hip_runtime.h>

typedef __attribute__((ext_vector_type(4))) float f32x4;
typedef __attribute__((ext_vector_type(2))) float f32x2;
typedef __attribute__((ext_vector_type(8))) short s16x8;

static __device__ __forceinline__ unsigned short f2bf(float f) {
  unsigned int u = __builtin_bit_cast(unsigned int, f);
  u += 0x7fffu + ((u >> 16) & 1u);   // round-to-nearest-even
  return (unsigned short)(u >> 16);
}
static __device__ __forceinline__ float bf2f(unsigned short h) {
  unsigned int u = ((unsigned int)h) << 16;
  return __builtin_bit_cast(float, u);
}

// ---------------- utility ----------------
__global__ void zero_k(int* p, int n) {
  int i = blockIdx.x * 256 + threadIdx.x;
  if (i < n) p[i] = 0;
}
__global__ void deg_count_k(const int* __restrict__ edges, int* cnt, int E) {
  int e = blockIdx.x * 256 + threadIdx.x;
  if (e < E) atomicAdd(&cnt[edges[E + e]], 1);
}

// ---------------- prefix scan (exclusive) over cnt -> row offsets ----------------
__global__ __launch_bounds__(256) void scan1_k(const int* __restrict__ cnt,
                                               int* __restrict__ loc,
                                               int* __restrict__ bsum, int N) {
  int t = threadIdx.x;
  int i0 = blockIdx.x * 1024 + t * 4;
  int c[4];
#pragma unroll
  for (int j = 0; j < 4; ++j) c[j] = (i0 + j < N) ? cnt[i0 + j] : 0;
  int tsum = c[0] + c[1] + c[2] + c[3];
  int lane = t & 63, wv = t >> 6;
  int incl = tsum;
#pragma unroll
  for (int off = 1; off < 64; off <<= 1) {
    int u = __shfl_up(incl, off, 64);
    if (lane >= off) incl += u;
  }
  __shared__ int ws[4];
  if (lane == 63) ws[wv] = incl;
  __syncthreads();
  int wbase = 0;
  for (int w = 0; w < wv; ++w) wbase += ws[w];
  int run = wbase + incl - tsum;
#pragma unroll
  for (int j = 0; j < 4; ++j) {
    if (i0 + j < N) loc[i0 + j] = run;
    run += c[j];
  }
  if (t == 255) bsum[blockIdx.x] = wbase + incl;
}
__global__ void scan2_k(int* bsum, int nb) {
  int lane = threadIdx.x;
  int v = (lane < nb) ? bsum[lane] : 0;
  int incl = v;
#pragma unroll
  for (int off = 1; off < 64; off <<= 1) {
    int u = __shfl_up(incl, off, 64);
    if (lane >= off) incl += u;
  }
  if (lane < nb) bsum[lane] = incl - v;
}
// add block offsets + init cursor + compute dinv (fused)
__global__ void addoff_k(int* loc, int* cursor, const int* __restrict__ bsum,
                         const int* __restrict__ cnt, float* __restrict__ dinv, int N) {
  int i = blockIdx.x * 256 + threadIdx.x;
  if (i < N) {
    int v = loc[i] + bsum[i >> 10];
    loc[i] = v;
    cursor[i] = v;
    dinv[i] = rsqrtf((float)(cnt[i] + 1));   // +1 self-loop
  }
}
__global__ void fill_k(const int* __restrict__ edges, int* cursor,
                       int* __restrict__ csr, int E) {
  int e = blockIdx.x * 256 + threadIdx.x;
  if (e < E) {
    int s = edges[e], d = edges[E + e];
    int pos = atomicAdd(&cursor[d], 1);
    csr[pos] = s;
  }
}

// ---------------- weight transpose + bf16 convert (LDS-tiled, both sides coalesced) ----------------
__global__ __launch_bounds__(256) void convw_k(const float* __restrict__ W,
                                               unsigned short* __restrict__ Wt,
                                               int K, int Nn) {
  __shared__ float t[32][33];
  const int tx = threadIdx.x & 31, ty = threadIdx.x >> 5;
  const int k0 = blockIdx.x * 32, n0 = blockIdx.y * 32;
#pragma unroll
  for (int r = 0; r < 32; r += 8)
    t[r + ty][tx] = W[(long long)(k0 + r + ty) * Nn + (n0 + tx)];
  __syncthreads();
#pragma unroll
  for (int r = 0; r < 32; r += 8)
    Wt[(long long)(n0 + r + ty) * K + (k0 + tx)] = f2bf(t[tx][r + ty]);
}

// ---------------- bf16 MFMA GEMM: LDS-free, barrier-free, direct-from-cache fragments ----------------
// gemm1 is a BANDWIDTH kernel (A = 307 MB read-once; MFMA needs only 16 us) -> the design goal
// is an unobstructed A stream. 8 waves/block (512 thr), each wave owns a 32-row x (NTOT/2)-col
// output tile. A fragments: per-lane direct nt loads (per row 4 quads x 32B = 128B contiguous).
// B fragments: per-lane direct loads from Bt (768KB -> L2-resident; the 4 waves with the same
// N-half on a CU read identical lines -> L1 broadcast). No __shared__, no s_barrier anywhere:
// register double-buffer with static names; loads free-run across K.
template <int KTOT, int NTOT, bool A_BF16>
__global__ __launch_bounds__(512, 2) void gemm_k(
    const void* __restrict__ Aptr, const unsigned short* __restrict__ Bt,
    const float* __restrict__ dinv, unsigned short* __restrict__ outg, int M) {
  constexpr int BK = 32;
  constexpr int NT = KTOT / BK;          // 48 / 8 (even)
  constexpr int STRIP = NTOT / 2;        // 128 / 64
  constexpr int NF = STRIP / 16;         // 8 / 4
  constexpr int MI = 2;                  // 32 rows per wave

  const int tid = threadIdx.x;
  const int wave = tid >> 6;             // 0..7
  const int lane = tid & 63;
  const int fr = lane & 15;
  const int quad = lane >> 4;
  const int mq = wave >> 1;              // 0..3  (M quarter)
  const int nh = wave & 1;               // 0..1  (N half)
  const int m0 = blockIdx.x * 128 + mq * 32;

  // clamped A row bases (uniform load counts; rows >= M feed dead outputs)
  const float* Af = (const float*)Aptr;
  const unsigned short* Ah = (const unsigned short*)Aptr;
  long long ar0 = (long long)min(m0 + 0 * 16 + fr, M - 1) * KTOT;
  long long ar1 = (long long)min(m0 + 1 * 16 + fr, M - 1) * KTOT;
  // B row base: row (nh*STRIP + ni*16 + fr) of Bt[NTOT][KTOT]
  const unsigned short* bbase = Bt + (long long)(nh * STRIP + fr) * KTOT;

  f32x4 acc[MI][NF];
#pragma unroll
  for (int i = 0; i < MI; ++i)
#pragma unroll
    for (int j = 0; j < NF; ++j) { f32x4 z = {0.f, 0.f, 0.f, 0.f}; acc[i][j] = z; }

  // prefetch buffers (two static sets -> register-resident, no scratch)
  f32x4 vaA[MI][2], vaB[MI][2];          // fp32 A path (cvt at consume time)
  s16x8 ahA[MI], ahB[MI];                // bf16 A path
  s16x8 bfA[NF], bfB[NF];

#define LDA_(VA, AH, KT)                                                       \
  do {                                                                         \
    const int k0_ = (KT) * BK + quad * 8;                                      \
    if constexpr (A_BF16) {                                                    \
      AH[0] = __builtin_nontemporal_load((const s16x8*)(Ah + ar0 + k0_));      \
      AH[1] = __builtin_nontemporal_load((const s16x8*)(Ah + ar1 + k0_));      \
    } else {                                                                   \
      VA[0][0] = __builtin_nontemporal_load((const f32x4*)(Af + ar0 + k0_));   \
      VA[0][1] = __builtin_nontemporal_load((const f32x4*)(Af + ar0 + k0_ + 4));\
      VA[1][0] = __builtin_nontemporal_load((const f32x4*)(Af + ar1 + k0_));   \
      VA[1][1] = __builtin_nontemporal_load((const f32x4*)(Af + ar1 + k0_ + 4));\
    }                                                                          \
  } while (0)

#define LDB_(BF, KT)                                                           \
  do {                                                                         \
    const int k0_ = (KT) * BK + quad * 8;                                      \
    _Pragma("unroll") for (int ni = 0; ni < NF; ++ni)                          \
        BF[ni] = *(const s16x8*)(bbase + (long long)ni * 16 * KTOT + k0_);     \
  } while (0)

#define MM_(VA, AH, BF)                                                        \
  do {                                                                         \
    s16x8 af_[MI];                                                             \
    if constexpr (A_BF16) {                                                    \
      af_[0] = AH[0]; af_[1] = AH[1];                                          \
    } else {                                                                   \
      _Pragma("unroll") for (int mi = 0; mi < MI; ++mi) {                      \
        s16x8 h_;                                                              \
        _Pragma("unroll") for (int j = 0; j < 4; ++j) {                        \
          h_[j] = (short)f2bf(VA[mi][0][j]);                                   \
          h_[4 + j] = (short)f2bf(VA[mi][1][j]);                               \
        }                                                                      \
        af_[mi] = h_;                                                          \
      }                                                                        \
    }                                                                          \
    _Pragma("unroll") for (int mi = 0; mi < MI; ++mi)                          \
      _Pragma("unroll") for (int ni = 0; ni < NF; ++ni)                        \
          acc[mi][ni] = __builtin_amdgcn_mfma_f32_16x16x32_bf16(               \
              af_[mi], BF[ni], acc[mi][ni], 0, 0, 0);                          \
  } while (0)

  // prologue
  LDA_(vaA, ahA, 0);
  LDB_(bfA, 0);

  // main loop: 2 K-steps per trip, static A/B buffer names
  for (int kp = 0; kp < NT / 2; ++kp) {
    const int kt = 2 * kp;
    LDA_(vaB, ahB, kt + 1);
    LDB_(bfB, kt + 1);
    MM_(vaA, ahA, bfA);
    if (kt + 2 < NT) {
      LDA_(vaA, ahA, kt + 2);
      LDB_(bfA, kt + 2);
    }
    MM_(vaB, ahB, bfB);
  }
#undef LDA_
#undef LDB_
#undef MM_

  // epilogue: C/D layout col=lane&15, row=quad*4+r; write node-major, dinv-scaled
#pragma unroll
  for (int mi = 0; mi < MI; ++mi) {
    int mbase = m0 + mi * 16 + quad * 4;
#pragma unroll
    for (int r = 0; r < 4; ++r) {
      int gm = mbase + r;
      if (gm < M) {
        float dv = dinv[gm];
#pragma unroll
        for (int ni = 0; ni < NF; ++ni) {
          int col = nh * STRIP + ni * 16 + fr;
          outg[(long long)gm * NTOT + col] = f2bf(acc[mi][ni][r] * dv);
        }
      }
    }
  }
}

// ---------------- agg layer 1: one wave per node, 2 row-groups x 32 lanes x 16B ----------------
__global__ __launch_bounds__(256) void agg1_k(const int* __restrict__ csr,
                                              const int* __restrict__ row,
                                              const int* __restrict__ cnt,
                                              const unsigned short* __restrict__ g,
                                              const float* __restrict__ bias,
                                              const float* __restrict__ dinv,
                                              unsigned short* __restrict__ h, int N) {
  const int wave = threadIdx.x >> 6, lane = threadIdx.x & 63;
  const int node = blockIdx.x * 4 + wave;
  if (node >= N) return;
  const int grp = lane >> 5, sub = lane & 31;
  const int f0 = sub * 8;
  float s[8];
#pragma unroll
  for (int k = 0; k < 8; ++k) s[k] = 0.0f;
  const int start = row[node], len = cnt[node];
  int j = 0;
  for (; j + 8 <= len; j += 8) {
    int idx[4];
#pragma unroll
    for (int t = 0; t < 4; ++t) idx[t] = csr[start + j + t * 2 + grp];
    s16x8 v[4];
#pragma unroll
    for (int t = 0; t < 4; ++t) v[t] = *(const s16x8*)&g[(long long)idx[t] * 256 + f0];
#pragma unroll
    for (int t = 0; t < 4; ++t)
#pragma unroll
      for (int k = 0; k < 8; ++k) s[k] += bf2f((unsigned short)v[t][k]);
  }
  for (; j < len; j += 2) {
    int jt = j + grp;
    bool val = jt < len;
    int idx = csr[start + (val ? jt : 0)];
    s16x8 v = *(const s16x8*)&g[(long long)idx * 256 + f0];
    float m = val ? 1.0f : 0.0f;
#pragma unroll
    for (int k = 0; k < 8; ++k) s[k] += m * bf2f((unsigned short)v[k]);
  }
#pragma unroll
  for (int k = 0; k < 8; ++k) s[k] += __shfl_xor(s[k], 32, 64);
  s16x8 sv = *(const s16x8*)&g[(long long)node * 256 + f0];
#pragma unroll
  for (int k = 0; k < 8; ++k) s[k] += bf2f((unsigned short)sv[k]);
  const float dv = dinv[node];
  f32x4 b0 = *(const f32x4*)&bias[f0];
  f32x4 b1v = *(const f32x4*)&bias[f0 + 4];
  if (grp == 0) {
    s16x8 o;
#pragma unroll
    for (int k = 0; k < 4; ++k) o[k] = (short)f2bf(fmaxf(0.0f, b0[k] + dv * s[k]));
#pragma unroll
    for (int k = 0; k < 4; ++k) o[4 + k] = (short)f2bf(fmaxf(0.0f, b1v[k] + dv * s[4 + k]));
    *(s16x8*)&h[(long long)node * 256 + f0] = o;
  }
}

// ---------------- agg layer 2 + fused L2-normalize: 4 groups x 16 lanes x 16B ----------------
__global__ __launch_bounds__(256) void agg2_k(const int* __restrict__ csr,
                                              const int* __restrict__ row,
                                              const int* __restrict__ cnt,
                                              const unsigned short* __restrict__ g,
                                              const float* __restrict__ b2,
                                              const float* __restrict__ dinv,
                                              float* __restrict__ out, int N) {
  const int wave = threadIdx.x >> 6, lane = threadIdx.x & 63;
  const int node = blockIdx.x * 4 + wave;
  if (node >= N) return;
  const int grp = lane >> 4, sub = lane & 15;
  const int f0 = sub * 8;
  float s[8];
#pragma unroll
  for (int k = 0; k < 8; ++k) s[k] = 0.0f;
  const int start = row[node], len = cnt[node];
  int j = 0;
  for (; j + 8 <= len; j += 8) {
    int idx[2];
#pragma unroll
    for (int t = 0; t < 2; ++t) idx[t] = csr[start + j + t * 4 + grp];
    s16x8 v[2];
#pragma unroll
    for (int t = 0; t < 2; ++t) v[t] = *(const s16x8*)&g[(long long)idx[t] * 128 + f0];
#pragma unroll
    for (int t = 0; t < 2; ++t)
#pragma unroll
      for (int k = 0; k < 8; ++k) s[k] += bf2f((unsigned short)v[t][k]);
  }
  for (; j < len; j += 4) {
    int jt = j + grp;
    bool val = jt < len;
    int idx = csr[start + (val ? jt : 0)];
    s16x8 v = *(const s16x8*)&g[(long long)idx * 128 + f0];
    float m = val ? 1.0f : 0.0f;
#pragma unroll
    for (int k = 0; k < 8; ++k) s[k] += m * bf2f((unsigned short)v[k]);
  }
#pragma unroll
  for (int k = 0; k < 8; ++k) s[k] += __shfl_xor(s[k], 16, 64);
#pragma unroll
  for (int k = 0; k < 8; ++k) s[k] += __shfl_xor(s[k], 32, 64);
  s16x8 sv = *(const s16x8*)&g[(long long)node * 128 + f0];
#pragma unroll
  for (int k = 0; k < 8; ++k) s[k] += bf2f((unsigned short)sv[k]);
  const float dv = dinv[node];
  f32x4 b0 = *(const f32x4*)&b2[f0];
  f32x4 b1v = *(const f32x4*)&b2[f0 + 4];
  float x[8];
#pragma unroll
  for (int k = 0; k < 4; ++k) x[k] = b0[k] + dv * s[k];
#pragma unroll
  for (int k = 0; k < 4; ++k) x[4 + k] = b1v[k] + dv * s[4 + k];
  float ss = 0.0f;
#pragma unroll
  for (int k = 0; k < 8; ++k) ss += x[k] * x[k];
#pragma unroll
  for (int off = 1; off < 16; off <<= 1) ss += __shfl_xor(ss, off, 64);
  const float inv = 1.0f / fmaxf(sqrtf(ss), 1e-12f);
  if (grp == 0) {
    f32x4 o0 = {x[0] * inv, x[1] * inv, x[2] * inv, x[3] * inv};
    f32x4 o1 = {x[4] * inv, x[5] * inv, x[6] * inv, x[7] * inv};
    *(f32x4*)&out[(long long)node * 128 + f0] = o0;
    *(f32x4*)&out[(long long)node * 128 + f0 + 4] = o1;
  }
}

extern "C" void kernel_launch(void* const* d_in, const int* in_sizes, int n_in,
                              void* d_out, int out_size, void* d_ws, size_t ws_size,
                              hipStream_t stream) {
  const float* x = (const float*)d_in[0];
  const int* edges = (const int*)d_in[1];
  const float* W1 = (const float*)d_in[2];
  const float* b1 = (const float*)d_in[3];
  const float* W2 = (const float*)d_in[4];
  const float* b2 = (const float*)d_in[5];
  float* out = (float*)d_out;

  const int HID = in_sizes[3];          // 256
  const int OUT = in_sizes[5];          // 128
  const int IN = in_sizes[2] / HID;     // 1536
  const int N = in_sizes[0] / IN;       // 50000
  const int E = in_sizes[1] / 2;        // 1600000

  size_t off = 0;
  auto carve = [&](size_t bytes) {
    void* p = (char*)d_ws + off;
    off += (bytes + 255) & ~(size_t)255;
    return p;
  };
  int* cnt = (int*)carve((size_t)N * 4);
  int* cursor = (int*)carve((size_t)N * 4);
  int* row = (int*)carve((size_t)N * 4);
  int* bsum = (int*)carve(64 * 4);
  int* csr = (int*)carve((size_t)E * 4 + 1024);
  float* dinv = (float*)carve((size_t)N * 4);
  unsigned short* W1t = (unsigned short*)carve((size_t)IN * HID * 2);
  unsigned short* W2t = (unsigned short*)carve((size_t)HID * OUT * 2);
  unsigned short* g1 = (unsigned short*)carve((size_t)N * HID * 2);
  unsigned short* acc1 = (unsigned short*)carve((size_t)N * HID * 2);
  unsigned short* g2 = (unsigned short*)carve((size_t)N * OUT * 2);
  (void)ws_size; (void)n_in; (void)out_size;

  const int nb = (N + 1023) / 1024;

  zero_k<<<(N + 255) / 256, 256, 0, stream>>>(cnt, N);
  deg_count_k<<<(E + 255) / 256, 256, 0, stream>>>(edges, cnt, E);

  scan1_k<<<nb, 256, 0, stream>>>(cnt, row, bsum, N);
  scan2_k<<<1, 64, 0, stream>>>(bsum, nb);
  addoff_k<<<(N + 255) / 256, 256, 0, stream>>>(row, cursor, bsum, cnt, dinv, N);
  fill_k<<<(E + 255) / 256, 256, 0, stream>>>(edges, cursor, csr, E);

  convw_k<<<dim3(IN / 32, HID / 32), 256, 0, stream>>>(W1, W1t, IN, HID);
  convw_k<<<dim3(HID / 32, OUT / 32), 256, 0, stream>>>(W2, W2t, HID, OUT);

  int mtiles = (N + 127) / 128;
  gemm_k<1536, 256, false><<<mtiles, 512, 0, stream>>>(x, W1t, dinv, g1, N);
  agg1_k<<<(N + 3) / 4, 256, 0, stream>>>(csr, row, cnt, g1, b1, dinv, acc1, N);
  gemm_k<256, 128, true><<<mtiles, 512, 0, stream>>>(acc1, W2t, dinv, g2, N);
  agg2_k<<<(N + 3) / 4, 256, 0, stream>>>(csr, row, cnt, g2, b2, dinv, out, N);
}

// Round 7
// 996.716 us; speedup vs baseline: 1.0517x; 1.0517x over previous
//
#include <hip/hip_runtime.h>

typedef __attribute__((ext_vector_type(4))) float f32x4;
typedef __attribute__((ext_vector_type(2))) float f32x2;
typedef __attribute__((ext_vector_type(8))) short s16x8;
typedef __attribute__((ext_vector_type(4))) unsigned short u16x4;

static __device__ __forceinline__ unsigned short f2bf(float f) {
  unsigned int u = __builtin_bit_cast(unsigned int, f);
  u += 0x7fffu + ((u >> 16) & 1u);   // round-to-nearest-even
  return (unsigned short)(u >> 16);
}
static __device__ __forceinline__ float bf2f(unsigned short h) {
  unsigned int u = ((unsigned int)h) << 16;
  return __builtin_bit_cast(float, u);
}

// ---------------- utility ----------------
__global__ void zero_k(int* p, int n) {
  int i = blockIdx.x * 256 + threadIdx.x;
  if (i < n) p[i] = 0;
}
__global__ void deg_count_k(const int* __restrict__ edges, int* cnt, int E) {
  int e = blockIdx.x * 256 + threadIdx.x;
  if (e < E) atomicAdd(&cnt[edges[E + e]], 1);
}

// ---------------- prefix scan (exclusive) over cnt -> row offsets ----------------
__global__ __launch_bounds__(256) void scan1_k(const int* __restrict__ cnt,
                                               int* __restrict__ loc,
                                               int* __restrict__ bsum, int N) {
  int t = threadIdx.x;
  int i0 = blockIdx.x * 1024 + t * 4;
  int c[4];
#pragma unroll
  for (int j = 0; j < 4; ++j) c[j] = (i0 + j < N) ? cnt[i0 + j] : 0;
  int tsum = c[0] + c[1] + c[2] + c[3];
  int lane = t & 63, wv = t >> 6;
  int incl = tsum;
#pragma unroll
  for (int off = 1; off < 64; off <<= 1) {
    int u = __shfl_up(incl, off, 64);
    if (lane >= off) incl += u;
  }
  __shared__ int ws[4];
  if (lane == 63) ws[wv] = incl;
  __syncthreads();
  int wbase = 0;
  for (int w = 0; w < wv; ++w) wbase += ws[w];
  int run = wbase + incl - tsum;
#pragma unroll
  for (int j = 0; j < 4; ++j) {
    if (i0 + j < N) loc[i0 + j] = run;
    run += c[j];
  }
  if (t == 255) bsum[blockIdx.x] = wbase + incl;
}
__global__ void scan2_k(int* bsum, int nb) {
  int lane = threadIdx.x;
  int v = (lane < nb) ? bsum[lane] : 0;
  int incl = v;
#pragma unroll
  for (int off = 1; off < 64; off <<= 1) {
    int u = __shfl_up(incl, off, 64);
    if (lane >= off) incl += u;
  }
  if (lane < nb) bsum[lane] = incl - v;
}
// add block offsets + init cursor + compute dinv (fused)
__global__ void addoff_k(int* loc, int* cursor, const int* __restrict__ bsum,
                         const int* __restrict__ cnt, float* __restrict__ dinv, int N) {
  int i = blockIdx.x * 256 + threadIdx.x;
  if (i < N) {
    int v = loc[i] + bsum[i >> 10];
    loc[i] = v;
    cursor[i] = v;
    dinv[i] = rsqrtf((float)(cnt[i] + 1));   // +1 self-loop
  }
}
__global__ void fill_k(const int* __restrict__ edges, int* cursor,
                       int* __restrict__ csr, int E) {
  int e = blockIdx.x * 256 + threadIdx.x;
  if (e < E) {
    int s = edges[e], d = edges[E + e];
    int pos = atomicAdd(&cursor[d], 1);
    csr[pos] = s;
  }
}

// ---------------- weight transpose + bf16 convert (LDS-tiled, both sides coalesced) ----------------
__global__ __launch_bounds__(256) void convw_k(const float* __restrict__ W,
                                               unsigned short* __restrict__ Wt,
                                               int K, int Nn) {
  __shared__ float t[32][33];
  const int tx = threadIdx.x & 31, ty = threadIdx.x >> 5;
  const int k0 = blockIdx.x * 32, n0 = blockIdx.y * 32;
#pragma unroll
  for (int r = 0; r < 32; r += 8)
    t[r + ty][tx] = W[(long long)(k0 + r + ty) * Nn + (n0 + tx)];
  __syncthreads();
#pragma unroll
  for (int r = 0; r < 32; r += 8)
    Wt[(long long)(n0 + r + ty) * K + (k0 + tx)] = f2bf(t[tx][r + ty]);
}

// ---------------- bf16 MFMA GEMM: barrier-FREE, per-wave-private LDS A-transpose ----------------
// Theory: all barrier-synced LDS designs convoyed at ~185us; LDS-free had uncoalesced A.
// Here: 8 waves/block, each owns 32 rows x (NTOT/2) cols. A staged per wave through a PRIVATE
// 2.3KB LDS region: coalesced global loads (8 rows x 128B contiguous segments per instr) ->
// cvt -> ds_write -> ds_read fragments. All ordering wave-local (compiler lgkm/vm counts);
// ZERO s_barrier, zero inline asm, waves slip freely. B read direct from L1/L2 (panel <=786KB,
// L2-resident; 4 waves per N-half share lines), register double-buffered, issued before MFMA.
// A ring 2-deep (~2 iters of HBM latency cover).
template <int KTOT, int NTOT, bool A_BF16>
__global__ __launch_bounds__(512, 2) void gemm_k(
    const void* __restrict__ Aptr, const unsigned short* __restrict__ Bt,
    const float* __restrict__ dinv, unsigned short* __restrict__ outg, int M) {
  constexpr int BK = 32;
  constexpr int NT = KTOT / BK;          // 48 / 8 (even)
  constexpr int STRIP = NTOT / 2;        // 128 / 64
  constexpr int NF = STRIP / 16;         // 8 / 4
  constexpr int MI = 2;                  // 32 rows per wave
  constexpr int LDAW = 36;               // LDS row stride in shorts (32 + 4 pad)
  constexpr int WLDS = 2 * 32 * LDAW;    // per-wave LDS shorts (2 buffers)

  __shared__ unsigned short Als[8 * WLDS];

  const int tid = threadIdx.x;
  const int wave = tid >> 6;             // 0..7
  const int lane = tid & 63;
  const int fr = lane & 15;
  const int quad = lane >> 4;
  const int mq = wave >> 1;              // 0..3  (M quarter)
  const int nh = wave & 1;               // 0..1  (N half)
  const int m0 = blockIdx.x * 128 + mq * 32;

  unsigned short* wl = &Als[wave * WLDS];

  const float* Af = (const float*)Aptr;
  const unsigned short* Ah = (const unsigned short*)Aptr;
  // clamped per-lane global A row bases (uniform counts; rows >= M feed dead outputs)
  long long arf[4];   // fp32 path: instr i -> row i*8 + (lane>>3), col (lane&7)*4 floats
  long long arh[2];   // bf16 path: instr i -> row i*16 + (lane>>2), col (lane&3)*8 shorts
#pragma unroll
  for (int i = 0; i < 4; ++i)
    arf[i] = (long long)min(m0 + i * 8 + (lane >> 3), M - 1) * KTOT + (lane & 7) * 4;
#pragma unroll
  for (int i = 0; i < 2; ++i)
    arh[i] = (long long)min(m0 + i * 16 + (lane >> 2), M - 1) * KTOT + (lane & 3) * 8;

  const unsigned short* bbase = Bt + (long long)(nh * STRIP + fr) * KTOT + quad * 8;

  f32x4 acc[MI][NF];
#pragma unroll
  for (int i = 0; i < MI; ++i)
#pragma unroll
    for (int j = 0; j < NF; ++j) { f32x4 z = {0.f, 0.f, 0.f, 0.f}; acc[i][j] = z; }

  f32x4 va0[4], va1[4];                  // fp32 A ring
  s16x8 ah0[2], ah1[2];                  // bf16 A ring
  s16x8 b0[NF], b1[NF];                  // B double buffer

#define LA_(VA, AH, KT)                                                        \
  do {                                                                         \
    const int ko_ = (KT) * BK;                                                 \
    if constexpr (A_BF16) {                                                    \
      _Pragma("unroll") for (int i = 0; i < 2; ++i)                            \
          AH[i] = __builtin_nontemporal_load((const s16x8*)(Ah + arh[i] + ko_));\
    } else {                                                                   \
      _Pragma("unroll") for (int i = 0; i < 4; ++i)                            \
          VA[i] = __builtin_nontemporal_load((const f32x4*)(Af + arf[i] + ko_));\
    }                                                                          \
  } while (0)

#define CW_(VA, AH, BUF)                                                       \
  do {                                                                         \
    if constexpr (A_BF16) {                                                    \
      _Pragma("unroll") for (int i = 0; i < 2; ++i) {                          \
        int r_ = i * 16 + (lane >> 2);                                         \
        *(s16x8*)&wl[(BUF) * (32 * LDAW) + r_ * LDAW + (lane & 3) * 8] = AH[i];\
      }                                                                        \
    } else {                                                                   \
      _Pragma("unroll") for (int i = 0; i < 4; ++i) {                          \
        u16x4 h_;                                                              \
        _Pragma("unroll") for (int j = 0; j < 4; ++j) h_[j] = f2bf(VA[i][j]);  \
        int r_ = i * 8 + (lane >> 3);                                          \
        *(u16x4*)&wl[(BUF) * (32 * LDAW) + r_ * LDAW + (lane & 7) * 4] = h_;   \
      }                                                                        \
    }                                                                          \
  } while (0)

#define RD_(AF, BUF)                                                           \
  do {                                                                         \
    _Pragma("unroll") for (int mi = 0; mi < MI; ++mi)                          \
        AF[mi] = *(const s16x8*)&wl[(BUF) * (32 * LDAW) +                      \
                                    (mi * 16 + fr) * LDAW + quad * 8];         \
  } while (0)

#define LB_(BF, KT)                                                            \
  do {                                                                         \
    const int ko_ = (KT) * BK;                                                 \
    _Pragma("unroll") for (int ni = 0; ni < NF; ++ni)                          \
        BF[ni] = *(const s16x8*)(bbase + (long long)ni * 16 * KTOT + ko_);     \
  } while (0)

#define MM_(AF, BF)                                                            \
  do {                                                                         \
    _Pragma("unroll") for (int mi = 0; mi < MI; ++mi)                          \
      _Pragma("unroll") for (int ni = 0; ni < NF; ++ni)                        \
          acc[mi][ni] = __builtin_amdgcn_mfma_f32_16x16x32_bf16(               \
              AF[mi], BF[ni], acc[mi][ni], 0, 0, 0);                           \
  } while (0)

  // ---- prologue: tile0 -> buf0; ring holds tiles 1 (va0/ah0) and 2 (va1/ah1); B tile0 ----
  LA_(va0, ah0, 0);
  CW_(va0, ah0, 0);
  LA_(va0, ah0, 1);
  LA_(va1, ah1, 2);
  LB_(b0, 0);

  // ---- main loop: 2 K-steps per trip, all buffer names static ----
  for (int kp = 0; kp < NT / 2; ++kp) {
    const int k = 2 * kp;
    {  // even step: compute tile k from buf0
      s16x8 af[MI];
      RD_(af, 0);
      LB_(b1, k + 1);                            // k+1 <= NT-1 always
      MM_(af, b0);
      CW_(va0, ah0, 1);                          // A(k+1) -> buf1
      const int kl = (k + 3 < NT) ? (k + 3) : (NT - 1);
      LA_(va0, ah0, kl);
    }
    {  // odd step: compute tile k+1 from buf1
      s16x8 af[MI];
      RD_(af, 1);
      const int kb = (k + 2 < NT) ? (k + 2) : (NT - 1);  // dead near tail
      LB_(b0, kb);
      MM_(af, b1);
      CW_(va1, ah1, 0);                          // A(k+2) -> buf0 (dead on last trip)
      const int kl = (k + 4 < NT) ? (k + 4) : (NT - 1);
      LA_(va1, ah1, kl);
    }
  }
#undef LA_
#undef CW_
#undef RD_
#undef LB_
#undef MM_

  // epilogue: C/D layout col=lane&15, row=quad*4+r; write node-major, dinv-scaled
#pragma unroll
  for (int mi = 0; mi < MI; ++mi) {
    int mbase = m0 + mi * 16 + quad * 4;
#pragma unroll
    for (int r = 0; r < 4; ++r) {
      int gm = mbase + r;
      if (gm < M) {
        float dv = dinv[gm];
#pragma unroll
        for (int ni = 0; ni < NF; ++ni) {
          int col = nh * STRIP + ni * 16 + fr;
          outg[(long long)gm * NTOT + col] = f2bf(acc[mi][ni][r] * dv);
        }
      }
    }
  }
}

// ---------------- agg layer 1: one wave per node, 2 row-groups x 32 lanes x 16B ----------------
__global__ __launch_bounds__(256) void agg1_k(const int* __restrict__ csr,
                                              const int* __restrict__ row,
                                              const int* __restrict__ cnt,
                                              const unsigned short* __restrict__ g,
                                              const float* __restrict__ bias,
                                              const float* __restrict__ dinv,
                                              unsigned short* __restrict__ h, int N) {
  const int wave = threadIdx.x >> 6, lane = threadIdx.x & 63;
  const int node = blockIdx.x * 4 + wave;
  if (node >= N) return;
  const int grp = lane >> 5, sub = lane & 31;
  const int f0 = sub * 8;
  float s[8];
#pragma unroll
  for (int k = 0; k < 8; ++k) s[k] = 0.0f;
  const int start = row[node], len = cnt[node];
  int j = 0;
  for (; j + 8 <= len; j += 8) {
    int idx[4];
#pragma unroll
    for (int t = 0; t < 4; ++t) idx[t] = csr[start + j + t * 2 + grp];
    s16x8 v[4];
#pragma unroll
    for (int t = 0; t < 4; ++t) v[t] = *(const s16x8*)&g[(long long)idx[t] * 256 + f0];
#pragma unroll
    for (int t = 0; t < 4; ++t)
#pragma unroll
      for (int k = 0; k < 8; ++k) s[k] += bf2f((unsigned short)v[t][k]);
  }
  for (; j < len; j += 2) {
    int jt = j + grp;
    bool val = jt < len;
    int idx = csr[start + (val ? jt : 0)];
    s16x8 v = *(const s16x8*)&g[(long long)idx * 256 + f0];
    float m = val ? 1.0f : 0.0f;
#pragma unroll
    for (int k = 0; k < 8; ++k) s[k] += m * bf2f((unsigned short)v[k]);
  }
#pragma unroll
  for (int k = 0; k < 8; ++k) s[k] += __shfl_xor(s[k], 32, 64);
  s16x8 sv = *(const s16x8*)&g[(long long)node * 256 + f0];
#pragma unroll
  for (int k = 0; k < 8; ++k) s[k] += bf2f((unsigned short)sv[k]);
  const float dv = dinv[node];
  f32x4 b0 = *(const f32x4*)&bias[f0];
  f32x4 b1v = *(const f32x4*)&bias[f0 + 4];
  if (grp == 0) {
    s16x8 o;
#pragma unroll
    for (int k = 0; k < 4; ++k) o[k] = (short)f2bf(fmaxf(0.0f, b0[k] + dv * s[k]));
#pragma unroll
    for (int k = 0; k < 4; ++k) o[4 + k] = (short)f2bf(fmaxf(0.0f, b1v[k] + dv * s[4 + k]));
    *(s16x8*)&h[(long long)node * 256 + f0] = o;
  }
}

// ---------------- agg layer 2 + fused L2-normalize: 4 groups x 16 lanes x 16B ----------------
__global__ __launch_bounds__(256) void agg2_k(const int* __restrict__ csr,
                                              const int* __restrict__ row,
                                              const int* __restrict__ cnt,
                                              const unsigned short* __restrict__ g,
                                              const float* __restrict__ b2,
                                              const float* __restrict__ dinv,
                                              float* __restrict__ out, int N) {
  const int wave = threadIdx.x >> 6, lane = threadIdx.x & 63;
  const int node = blockIdx.x * 4 + wave;
  if (node >= N) return;
  const int grp = lane >> 4, sub = lane & 15;
  const int f0 = sub * 8;
  float s[8];
#pragma unroll
  for (int k = 0; k < 8; ++k) s[k] = 0.0f;
  const int start = row[node], len = cnt[node];
  int j = 0;
  for (; j + 8 <= len; j += 8) {
    int idx[2];
#pragma unroll
    for (int t = 0; t < 2; ++t) idx[t] = csr[start + j + t * 4 + grp];
    s16x8 v[2];
#pragma unroll
    for (int t = 0; t < 2; ++t) v[t] = *(const s16x8*)&g[(long long)idx[t] * 128 + f0];
#pragma unroll
    for (int t = 0; t < 2; ++t)
#pragma unroll
      for (int k = 0; k < 8; ++k) s[k] += bf2f((unsigned short)v[t][k]);
  }
  for (; j < len; j += 4) {
    int jt = j + grp;
    bool val = jt < len;
    int idx = csr[start + (val ? jt : 0)];
    s16x8 v = *(const s16x8*)&g[(long long)idx * 128 + f0];
    float m = val ? 1.0f : 0.0f;
#pragma unroll
    for (int k = 0; k < 8; ++k) s[k] += m * bf2f((unsigned short)v[k]);
  }
#pragma unroll
  for (int k = 0; k < 8; ++k) s[k] += __shfl_xor(s[k], 16, 64);
#pragma unroll
  for (int k = 0; k < 8; ++k) s[k] += __shfl_xor(s[k], 32, 64);
  s16x8 sv = *(const s16x8*)&g[(long long)node * 128 + f0];
#pragma unroll
  for (int k = 0; k < 8; ++k) s[k] += bf2f((unsigned short)sv[k]);
  const float dv = dinv[node];
  f32x4 b0 = *(const f32x4*)&b2[f0];
  f32x4 b1v = *(const f32x4*)&b2[f0 + 4];
  float x[8];
#pragma unroll
  for (int k = 0; k < 4; ++k) x[k] = b0[k] + dv * s[k];
#pragma unroll
  for (int k = 0; k < 4; ++k) x[4 + k] = b1v[k] + dv * s[4 + k];
  float ss = 0.0f;
#pragma unroll
  for (int k = 0; k < 8; ++k) ss += x[k] * x[k];
#pragma unroll
  for (int off = 1; off < 16; off <<= 1) ss += __shfl_xor(ss, off, 64);
  const float inv = 1.0f / fmaxf(sqrtf(ss), 1e-12f);
  if (grp == 0) {
    f32x4 o0 = {x[0] * inv, x[1] * inv, x[2] * inv, x[3] * inv};
    f32x4 o1 = {x[4] * inv, x[5] * inv, x[6] * inv, x[7] * inv};
    *(f32x4*)&out[(long long)node * 128 + f0] = o0;
    *(f32x4*)&out[(long long)node * 128 + f0 + 4] = o1;
  }
}

extern "C" void kernel_launch(void* const* d_in, const int* in_sizes, int n_in,
                              void* d_out, int out_size, void* d_ws, size_t ws_size,
                              hipStream_t stream) {
  const float* x = (const float*)d_in[0];
  const int* edges = (const int*)d_in[1];
  const float* W1 = (const float*)d_in[2];
  const float* b1 = (const float*)d_in[3];
  const float* W2 = (const float*)d_in[4];
  const float* b2 = (const float*)d_in[5];
  float* out = (float*)d_out;

  const int HID = in_sizes[3];          // 256
  const int OUT = in_sizes[5];          // 128
  const int IN = in_sizes[2] / HID;     // 1536
  const int N = in_sizes[0] / IN;       // 50000
  const int E = in_sizes[1] / 2;        // 1600000

  size_t off = 0;
  auto carve = [&](size_t bytes) {
    void* p = (char*)d_ws + off;
    off += (bytes + 255) & ~(size_t)255;
    return p;
  };
  int* cnt = (int*)carve((size_t)N * 4);
  int* cursor = (int*)carve((size_t)N * 4);
  int* row = (int*)carve((size_t)N * 4);
  int* bsum = (int*)carve(64 * 4);
  int* csr = (int*)carve((size_t)E * 4 + 1024);
  float* dinv = (float*)carve((size_t)N * 4);
  unsigned short* W1t = (unsigned short*)carve((size_t)IN * HID * 2);
  unsigned short* W2t = (unsigned short*)carve((size_t)HID * OUT * 2);
  unsigned short* g1 = (unsigned short*)carve((size_t)N * HID * 2);
  unsigned short* acc1 = (unsigned short*)carve((size_t)N * HID * 2);
  unsigned short* g2 = (unsigned short*)carve((size_t)N * OUT * 2);
  (void)ws_size; (void)n_in; (void)out_size;

  const int nb = (N + 1023) / 1024;

  zero_k<<<(N + 255) / 256, 256, 0, stream>>>(cnt, N);
  deg_count_k<<<(E + 255) / 256, 256, 0, stream>>>(edges, cnt, E);

  scan1_k<<<nb, 256, 0, stream>>>(cnt, row, bsum, N);
  scan2_k<<<1, 64, 0, stream>>>(bsum, nb);
  addoff_k<<<(N + 255) / 256, 256, 0, stream>>>(row, cursor, bsum, cnt, dinv, N);
  fill_k<<<(E + 255) / 256, 256, 0, stream>>>(edges, cursor, csr, E);

  convw_k<<<dim3(IN / 32, HID / 32), 256, 0, stream>>>(W1, W1t, IN, HID);
  convw_k<<<dim3(HID / 32, OUT / 32), 256, 0, stream>>>(W2, W2t, HID, OUT);

  int mtiles = (N + 127) / 128;
  gemm_k<1536, 256, false><<<mtiles, 512, 0, stream>>>(x, W1t, dinv, g1, N);
  agg1_k<<<(N + 3) / 4, 256, 0, stream>>>(csr, row, cnt, g1, b1, dinv, acc1, N);
  gemm_k<256, 128, true><<<mtiles, 512, 0, stream>>>(acc1, W2t, dinv, g2, N);
  agg2_k<<<(N + 3) / 4, 256, 0, stream>>>(csr, row, cnt, g2, b2, dinv, out, N);
}

// Round 8
// 940.099 us; speedup vs baseline: 1.1151x; 1.0602x over previous
//
#include <hip/hip_runtime.h>

typedef __attribute__((ext_vector_type(4))) float f32x4;
typedef __attribute__((ext_vector_type(2))) float f32x2;
typedef __attribute__((ext_vector_type(8))) short s16x8;
typedef __attribute__((ext_vector_type(4))) unsigned short u16x4;
typedef __attribute__((ext_vector_type(2))) unsigned short u16x2;

static __device__ __forceinline__ unsigned short f2bf(float f) {
  unsigned int u = __builtin_bit_cast(unsigned int, f);
  u += 0x7fffu + ((u >> 16) & 1u);   // round-to-nearest-even
  return (unsigned short)(u >> 16);
}
static __device__ __forceinline__ float bf2f(unsigned short h) {
  unsigned int u = ((unsigned int)h) << 16;
  return __builtin_bit_cast(float, u);
}

static __device__ __forceinline__ void gload_lds16(const void* g, void* l) {
  __builtin_amdgcn_global_load_lds(
      (const __attribute__((address_space(1))) unsigned int*)g,
      (__attribute__((address_space(3))) unsigned int*)l, 16, 0, 0);
}

// ---------------- utility ----------------
__global__ void zero_k(int* p, int n) {
  int i = blockIdx.x * 256 + threadIdx.x;
  if (i < n) p[i] = 0;
}
__global__ void deg_count_k(const int* __restrict__ edges, int* cnt, int E) {
  int e = blockIdx.x * 256 + threadIdx.x;
  if (e < E) atomicAdd(&cnt[edges[E + e]], 1);
}

// ---------------- prefix scan (exclusive) over cnt -> row offsets ----------------
__global__ __launch_bounds__(256) void scan1_k(const int* __restrict__ cnt,
                                               int* __restrict__ loc,
                                               int* __restrict__ bsum, int N) {
  int t = threadIdx.x;
  int i0 = blockIdx.x * 1024 + t * 4;
  int c[4];
#pragma unroll
  for (int j = 0; j < 4; ++j) c[j] = (i0 + j < N) ? cnt[i0 + j] : 0;
  int tsum = c[0] + c[1] + c[2] + c[3];
  int lane = t & 63, wv = t >> 6;
  int incl = tsum;
#pragma unroll
  for (int off = 1; off < 64; off <<= 1) {
    int u = __shfl_up(incl, off, 64);
    if (lane >= off) incl += u;
  }
  __shared__ int ws[4];
  if (lane == 63) ws[wv] = incl;
  __syncthreads();
  int wbase = 0;
  for (int w = 0; w < wv; ++w) wbase += ws[w];
  int run = wbase + incl - tsum;
#pragma unroll
  for (int j = 0; j < 4; ++j) {
    if (i0 + j < N) loc[i0 + j] = run;
    run += c[j];
  }
  if (t == 255) bsum[blockIdx.x] = wbase + incl;
}
__global__ void scan2_k(int* bsum, int nb) {
  int lane = threadIdx.x;
  int v = (lane < nb) ? bsum[lane] : 0;
  int incl = v;
#pragma unroll
  for (int off = 1; off < 64; off <<= 1) {
    int u = __shfl_up(incl, off, 64);
    if (lane >= off) incl += u;
  }
  if (lane < nb) bsum[lane] = incl - v;
}
// add block offsets + init cursor + compute dinv (fused)
__global__ void addoff_k(int* loc, int* cursor, const int* __restrict__ bsum,
                         const int* __restrict__ cnt, float* __restrict__ dinv, int N) {
  int i = blockIdx.x * 256 + threadIdx.x;
  if (i < N) {
    int v = loc[i] + bsum[i >> 10];
    loc[i] = v;
    cursor[i] = v;
    dinv[i] = rsqrtf((float)(cnt[i] + 1));   // +1 self-loop
  }
}
__global__ void fill_k(const int* __restrict__ edges, int* cursor,
                       int* __restrict__ csr, int E) {
  int e = blockIdx.x * 256 + threadIdx.x;
  if (e < E) {
    int s = edges[e], d = edges[E + e];
    int pos = atomicAdd(&cursor[d], 1);
    csr[pos] = s;
  }
}

// ---------------- weight transpose + bf16 convert (LDS-tiled, both sides coalesced) ----------------
__global__ __launch_bounds__(256) void convw_k(const float* __restrict__ W,
                                               unsigned short* __restrict__ Wt,
                                               int K, int Nn) {
  __shared__ float t[32][33];
  const int tx = threadIdx.x & 31, ty = threadIdx.x >> 5;
  const int k0 = blockIdx.x * 32, n0 = blockIdx.y * 32;
#pragma unroll
  for (int r = 0; r < 32; r += 8)
    t[r + ty][tx] = W[(long long)(k0 + r + ty) * Nn + (n0 + tx)];
  __syncthreads();
#pragma unroll
  for (int r = 0; r < 32; r += 8)
    Wt[(long long)(n0 + r + ty) * K + (k0 + tx)] = f2bf(t[tx][r + ty]);
}

// ---------------- bf16 MFMA GEMM (layer 1): 3-buffer stage-ahead-2, counted-vmcnt ----------------
// Verbatim round-5 fp32-A path (measured 183 us, passed). Output node-major, dinv-scaled bf16.
template <int KTOT, int NTOT>
__global__ __launch_bounds__(256, 2) void gemm1_k(
    const void* __restrict__ Aptr, const unsigned short* __restrict__ Bt,
    const float* __restrict__ dinv, unsigned short* __restrict__ outg, int M) {
  constexpr int BM = 128, BK = 32;
  constexpr int LDA = BK + 8;
  constexpr int MI = BM / 16;
  constexpr int STRIP = NTOT / 4;
  constexpr int NF = STRIP / 16;
  constexpr int BCH = (NTOT / 16) / 4;
  constexpr int NT = KTOT / BK;
  constexpr int TPR = 256 / BM;
  constexpr int FPT = BK / TPR;

  __shared__ unsigned short Asm_[3][BM * LDA];
  __shared__ unsigned short Bsm_[3][NTOT * BK];

  const int tid = threadIdx.x;
  const int wave = tid >> 6;
  const int lane = tid & 63;
  const int fr = lane & 15;
  const int quad = lane >> 4;
  const int m0 = blockIdx.x * BM;

  f32x4 acc[MI][NF];
#pragma unroll
  for (int i = 0; i < MI; ++i)
#pragma unroll
    for (int j = 0; j < NF; ++j) { f32x4 z = {0.f, 0.f, 0.f, 0.f}; acc[i][j] = z; }

  const int sl_r = lane >> 2;
  const int sl_s = (lane & 3) ^ ((lane >> 3) & 3);

  auto stageB = [&](int k0, int buf) {
#pragma unroll
    for (int c = 0; c < BCH; ++c) {
      int cc = wave * BCH + c;
      int r = cc * 16 + sl_r;
      const unsigned short* gp = Bt + (long long)r * KTOT + k0 + sl_s * 8;
      gload_lds16(gp, &Bsm_[buf][cc * 512]);
    }
  };

  const int sr = tid / TPR;
  const int sc = (tid % TPR) * FPT;
  const int arow = min(m0 + sr, M - 1);
  const float* arowf = (const float*)Aptr + (long long)arow * KTOT;
  float va0[FPT], va1[FPT], va2[FPT];

#define LOADA(VA, K0)                                                          \
  do {                                                                         \
    _Pragma("unroll") for (int c = 0; c < FPT / 4; ++c) {                      \
      f32x4 v = __builtin_nontemporal_load(                                    \
          (const f32x4*)(arowf + (K0) + sc + c * 4));                          \
      _Pragma("unroll") for (int j = 0; j < 4; ++j) VA[c * 4 + j] = v[j];      \
    }                                                                          \
  } while (0)

#define CVTWA(VA, BUF)                                                         \
  do {                                                                         \
    _Pragma("unroll") for (int c = 0; c < FPT / 8; ++c) {                      \
      s16x8 hh;                                                                \
      _Pragma("unroll") for (int j = 0; j < 8; ++j)                            \
          hh[j] = (short)f2bf(VA[c * 8 + j]);                                  \
      *(s16x8*)&Asm_[BUF][sr * LDA + sc + c * 8] = hh;                         \
    }                                                                          \
  } while (0)

  const int xsl = (fr >> 1) & 3;
  auto compute = [&](int cur) {
    s16x8 af[MI], bfr[NF];
#pragma unroll
    for (int mi = 0; mi < MI; ++mi)
      af[mi] = *(const s16x8*)&Asm_[cur][(mi * 16 + fr) * LDA + quad * 8];
#pragma unroll
    for (int ni = 0; ni < NF; ++ni)
      bfr[ni] = *(const s16x8*)&Bsm_[cur][(wave * STRIP + ni * 16 + fr) * BK + ((quad ^ xsl) << 3)];
#pragma unroll
    for (int mi = 0; mi < MI; ++mi)
#pragma unroll
      for (int ni = 0; ni < NF; ++ni)
        acc[mi][ni] = __builtin_amdgcn_mfma_f32_16x16x32_bf16(af[mi], bfr[ni], acc[mi][ni], 0, 0, 0);
  };

  // ---- prologue ----
  {
    float vt[FPT];
    LOADA(vt, 0);  CVTWA(vt, 0);
    LOADA(vt, BK); CVTWA(vt, 1);
  }
  stageB(0, 0);
  stageB(BK, 1);
  __builtin_amdgcn_sched_barrier(0);
  LOADA(va0, 2 * BK);
  LOADA(va1, 3 * BK);
  LOADA(va2, 4 * BK);

#define GITER(J, P, PS, VA)                                                    \
  {                                                                            \
    asm volatile("s_waitcnt vmcnt(12) lgkmcnt(0)" ::: "memory");               \
    __builtin_amdgcn_s_barrier();                                              \
    __builtin_amdgcn_sched_barrier(0);                                         \
    int ks_ = ((J) + 2 < NT) ? ((J) + 2) * BK : (KTOT - BK);                   \
    stageB(ks_, (PS));                                                         \
    __builtin_amdgcn_sched_barrier(0);                                         \
    CVTWA(VA, (PS));                                                           \
    int kl_ = ((J) + 5 < NT) ? ((J) + 5) * BK : (KTOT - BK);                   \
    LOADA(VA, kl_);                                                            \
    compute(P);                                                                \
  }

  int j = 0;
  for (; j + 3 <= NT; j += 3) {
    GITER(j, 0, 2, va0);
    GITER(j + 1, 1, 0, va1);
    GITER(j + 2, 2, 1, va2);
  }
  if constexpr (NT % 3 >= 1) GITER(j, 0, 2, va0);
  if constexpr (NT % 3 == 2) GITER(j + 1, 1, 0, va1);

#undef GITER
#undef LOADA
#undef CVTWA

#pragma unroll
  for (int mi = 0; mi < MI; ++mi) {
    int mbase = mi * 16 + quad * 4;
#pragma unroll
    for (int r = 0; r < 4; ++r) {
      int gm = m0 + mbase + r;
      if (gm < M) {
        float dv = dinv[gm];
#pragma unroll
        for (int ni = 0; ni < NF; ++ni) {
          int col = wave * STRIP + ni * 16 + fr;
          outg[(long long)gm * NTOT + col] = f2bf(acc[mi][ni][r] * dv);
        }
      }
    }
  }
}

// ---------------- agg layer 1 + FUSED gemm2 ----------------
// Round-0 gather shape (best measured): 1 node/wave, all 64 lanes read the SAME neighbor row
// (one fully-coalesced 512B line per edge), 8 edges in flight. Then, per node, the wave holds
// the full 256-feat h row (4 fp32/lane): write to wave-PRIVATE LDS row (no barrier; wave-local
// lgkm ordering), dot against block-shared bf16 W2 in LDS, emit g2 = bf16(dinv * (h @ W2)).
// Eliminates the gemm2 dispatch + acc1 write/read (51 MB). VALU dot hides under gather stalls.
__global__ __launch_bounds__(512) void agg1f_k(const int* __restrict__ csr,
                                               const int* __restrict__ row,
                                               const int* __restrict__ cnt,
                                               const unsigned short* __restrict__ g,
                                               const float* __restrict__ b1,
                                               const float* __restrict__ W2,   // [256][128] fp32
                                               const float* __restrict__ dinv,
                                               unsigned short* __restrict__ g2, // out [N][128] bf16
                                               int N) {
  __shared__ unsigned short W2s[256 * 128];   // 64 KB bf16
  __shared__ float rowb[8][260];              // per-wave h row (256 fp32 + pad)

  for (int i = threadIdx.x; i < 256 * 128; i += 512)
    W2s[i] = f2bf(W2[i]);
  __syncthreads();                            // once; no barriers in the node loop

  const int wave = threadIdx.x >> 6, lane = threadIdx.x & 63;
  const int f0 = lane << 2;                   // 4 feats of 256
  float* myrow = &rowb[wave][0];

  for (int node = blockIdx.x * 8 + wave; node < N; node += gridDim.x * 8) {
    // ---- gather phase (round-0 structure) ----
    u16x4 sv = *(const u16x4*)&g[(long long)node * 256 + f0];
    f32x4 s = {bf2f(sv[0]), bf2f(sv[1]), bf2f(sv[2]), bf2f(sv[3])};
    const int start = row[node], len = cnt[node];
    int j = 0;
    for (; j + 8 <= len; j += 8) {
      int idx[8];
#pragma unroll
      for (int t = 0; t < 8; ++t) idx[t] = csr[start + j + t];
      u16x4 v[8];
#pragma unroll
      for (int t = 0; t < 8; ++t) v[t] = *(const u16x4*)&g[(long long)idx[t] * 256 + f0];
#pragma unroll
      for (int t = 0; t < 8; ++t) {
        s[0] += bf2f(v[t][0]); s[1] += bf2f(v[t][1]);
        s[2] += bf2f(v[t][2]); s[3] += bf2f(v[t][3]);
      }
    }
    for (; j < len; ++j) {
      int i0 = csr[start + j];
      u16x4 v = *(const u16x4*)&g[(long long)i0 * 256 + f0];
      s[0] += bf2f(v[0]); s[1] += bf2f(v[1]); s[2] += bf2f(v[2]); s[3] += bf2f(v[3]);
    }
    const float dv = dinv[node];
    f32x4 b = *(const f32x4*)&b1[f0];
    f32x4 h;
#pragma unroll
    for (int k = 0; k < 4; ++k) h[k] = fmaxf(0.0f, b[k] + dv * s[k]);

    // ---- fused gemm2: g2[node][n] = bf16(dv * sum_k h[k] * W2[k][n]) ----
    *(f32x4*)&myrow[f0] = h;                  // wave-local ds_write; lgkm orders vs reads below
    float ga = 0.0f, gb = 0.0f;               // two accums (even/odd k) break the FMA chain
    float ga2 = 0.0f, gb2 = 0.0f;
#pragma unroll 4
    for (int kk = 0; kk < 64; ++kk) {
      f32x4 hv = *(const f32x4*)&myrow[kk * 4];           // broadcast read
#pragma unroll
      for (int t = 0; t < 4; ++t) {
        unsigned int wp = *(const unsigned int*)&W2s[(kk * 4 + t) * 128 + lane * 2];
        float w0 = bf2f((unsigned short)(wp & 0xffffu));
        float w1 = bf2f((unsigned short)(wp >> 16));
        if (t & 1) { ga2 += hv[t] * w0; gb2 += hv[t] * w1; }
        else       { ga  += hv[t] * w0; gb  += hv[t] * w1; }
      }
    }
    u16x2 o = {f2bf(dv * (ga + ga2)), f2bf(dv * (gb + gb2))};
    *(u16x2*)&g2[(long long)node * 128 + lane * 2] = o;
  }
}

// ---------------- agg layer 2 + fused L2-normalize (round-0 verbatim) ----------------
__global__ __launch_bounds__(256) void agg2_k(const int* __restrict__ csr,
                                              const int* __restrict__ row,
                                              const int* __restrict__ cnt,
                                              const unsigned short* __restrict__ g,
                                              const float* __restrict__ b2,
                                              const float* __restrict__ dinv,
                                              float* __restrict__ out, int N) {
  int node = blockIdx.x * 4 + (threadIdx.x >> 6);
  if (node >= N) return;
  int lane = threadIdx.x & 63;
  int f0 = lane << 1;
  u16x2 sv = *(const u16x2*)&g[(long long)node * 128 + f0];
  float s0 = bf2f(sv[0]), s1 = bf2f(sv[1]);
  int start = row[node], len = cnt[node];
  int j = 0;
  for (; j + 8 <= len; j += 8) {
    int idx[8];
#pragma unroll
    for (int t = 0; t < 8; ++t) idx[t] = csr[start + j + t];
    u16x2 v[8];
#pragma unroll
    for (int t = 0; t < 8; ++t) v[t] = *(const u16x2*)&g[(long long)idx[t] * 128 + f0];
#pragma unroll
    for (int t = 0; t < 8; ++t) { s0 += bf2f(v[t][0]); s1 += bf2f(v[t][1]); }
  }
  for (; j < len; ++j) {
    int i0 = csr[start + j];
    u16x2 v = *(const u16x2*)&g[(long long)i0 * 128 + f0];
    s0 += bf2f(v[0]); s1 += bf2f(v[1]);
  }
  float dv = dinv[node];
  f32x2 b = *(const f32x2*)&b2[f0];
  float x0 = b[0] + dv * s0;
  float x1 = b[1] + dv * s1;
  float ss = x0 * x0 + x1 * x1;
#pragma unroll
  for (int off = 32; off > 0; off >>= 1) ss += __shfl_xor(ss, off, 64);
  float inv = 1.0f / fmaxf(sqrtf(ss), 1e-12f);
  f32x2 o = {x0 * inv, x1 * inv};
  *(f32x2*)&out[(long long)node * 128 + f0] = o;
}

extern "C" void kernel_launch(void* const* d_in, const int* in_sizes, int n_in,
                              void* d_out, int out_size, void* d_ws, size_t ws_size,
                              hipStream_t stream) {
  const float* x = (const float*)d_in[0];
  const int* edges = (const int*)d_in[1];
  const float* W1 = (const float*)d_in[2];
  const float* b1 = (const float*)d_in[3];
  const float* W2 = (const float*)d_in[4];
  const float* b2 = (const float*)d_in[5];
  float* out = (float*)d_out;

  const int HID = in_sizes[3];          // 256
  const int OUT = in_sizes[5];          // 128
  const int IN = in_sizes[2] / HID;     // 1536
  const int N = in_sizes[0] / IN;       // 50000
  const int E = in_sizes[1] / 2;        // 1600000
  (void)OUT;

  size_t off = 0;
  auto carve = [&](size_t bytes) {
    void* p = (char*)d_ws + off;
    off += (bytes + 255) & ~(size_t)255;
    return p;
  };
  int* cnt = (int*)carve((size_t)N * 4);
  int* cursor = (int*)carve((size_t)N * 4);
  int* row = (int*)carve((size_t)N * 4);
  int* bsum = (int*)carve(64 * 4);
  int* csr = (int*)carve((size_t)E * 4 + 1024);
  float* dinv = (float*)carve((size_t)N * 4);
  unsigned short* W1t = (unsigned short*)carve((size_t)IN * HID * 2);
  unsigned short* g1 = (unsigned short*)carve((size_t)N * HID * 2);   // node-major [N][256]
  unsigned short* g2 = (unsigned short*)carve((size_t)N * OUT * 2);   // node-major [N][128]
  (void)ws_size; (void)n_in; (void)out_size;

  const int nb = (N + 1023) / 1024;

  zero_k<<<(N + 255) / 256, 256, 0, stream>>>(cnt, N);
  deg_count_k<<<(E + 255) / 256, 256, 0, stream>>>(edges, cnt, E);

  scan1_k<<<nb, 256, 0, stream>>>(cnt, row, bsum, N);
  scan2_k<<<1, 64, 0, stream>>>(bsum, nb);
  addoff_k<<<(N + 255) / 256, 256, 0, stream>>>(row, cursor, bsum, cnt, dinv, N);
  fill_k<<<(E + 255) / 256, 256, 0, stream>>>(edges, cursor, csr, E);

  convw_k<<<dim3(IN / 32, HID / 32), 256, 0, stream>>>(W1, W1t, IN, HID);

  int mtiles = (N + 127) / 128;
  gemm1_k<1536, 256><<<mtiles, 256, 0, stream>>>(x, W1t, dinv, g1, N);
  agg1f_k<<<512, 512, 0, stream>>>(csr, row, cnt, g1, b1, W2, dinv, g2, N);
  agg2_k<<<(N + 3) / 4, 256, 0, stream>>>(csr, row, cnt, g2, b2, dinv, out, N);
}